// Round 4
// baseline (420.477 us; speedup 1.0000x reference)
//
#include <hip/hip_runtime.h>

// PrunedMultiHeadAttention: B=16,N=1024,C=768,H=9,HD=64
// All f16 operand matrices live in global memory XOR-chunk-swizzled:
//   within each aligned group of 8 16B-chunks (64 elems = one BK tile),
//   logical chunk c of row r is stored at position (c & ~7) | ((c ^ r) & 7).
// This makes global_load_lds (lane-linear DMA into unpadded stride-64/128 LDS)
// conflict-free on the MFMA b128 fragment reads (group = (4ks+hi)^(lo&7)).

typedef _Float16 f16x8 __attribute__((ext_vector_type(8)));
typedef _Float16 f16x4 __attribute__((ext_vector_type(4)));
typedef __fp16   h16x2 __attribute__((ext_vector_type(2)));  // cvt_pkrtz result type
typedef float    f32x4 __attribute__((ext_vector_type(4)));

#define MFMA16(a, b, c) __builtin_amdgcn_mfma_f32_16x16x32_f16(a, b, c, 0, 0, 0)

// async global->LDS DMA, 16B/lane; LDS dest = wave-uniform base + lane*16
__device__ __forceinline__ void gld16(const _Float16* g, _Float16* l) {
  __builtin_amdgcn_global_load_lds((const __attribute__((address_space(1))) void*)g,
                                   (__attribute__((address_space(3))) void*)l, 16, 0, 0);
}

// ---------------------------------------------------------------- convert + swizzle
// fp32 row-major [rows_src x (cpr*8)] -> fp16 swizzled [rows_dst x (cpr*8)], zero-pad rows >= rows_src
__global__ __launch_bounds__(256) void cvt_swz(const float* __restrict__ src,
                                               _Float16* __restrict__ dst,
                                               int rows_src, int cpr, int total) {
  const int g = blockIdx.x * 256 + threadIdx.x;
  if (g >= total) return;
  const int row = g / cpr;
  const int c = g - row * cpr;
  const int L = cpr * 8;
  const int pos = (c & ~7) | ((c ^ row) & 7);
  union { f16x8 v; h16x2 h[4]; } u;
  if (row < rows_src) {
    const float4 a = *(const float4*)(src + row * L + c * 8);
    const float4 b = *(const float4*)(src + row * L + c * 8 + 4);
    u.h[0] = __builtin_amdgcn_cvt_pkrtz(a.x, a.y);
    u.h[1] = __builtin_amdgcn_cvt_pkrtz(a.z, a.w);
    u.h[2] = __builtin_amdgcn_cvt_pkrtz(b.x, b.y);
    u.h[3] = __builtin_amdgcn_cvt_pkrtz(b.z, b.w);
  } else {
    u.v = (f16x8){};
  }
  *(f16x8*)(dst + row * L + pos * 8) = u.v;
}

// ---------------------------------------------------------------- GEMM1: qkv = x @ W^T + b
// A: x16 swz [16384,768], Bw: w1 swz padded [1792,768] (rows >=1728 zero)
// Q -> [B,H,N,64] plain; K -> [B,H,N,64] swizzled; V -> [B,H,64,N] transposed+swizzled
__global__ __launch_bounds__(256, 4) void gemm1_qkv(const _Float16* __restrict__ A,
                                                    const _Float16* __restrict__ Bw,
                                                    const float* __restrict__ bias,
                                                    _Float16* __restrict__ Qo,
                                                    _Float16* __restrict__ Ko,
                                                    _Float16* __restrict__ Vt) {
  __shared__ __align__(16) _Float16 As[128 * 64];
  __shared__ __align__(16) _Float16 Bs[128 * 64];
  const int tid = threadIdx.x;
  const int wave = tid >> 6, lane = tid & 63;
  const int lo = lane & 15, hi = lane >> 4;
  const int wm = (wave >> 1) * 64, wn = (wave & 1) * 64;
  const int m0 = blockIdx.x * 128, n0 = blockIdx.y * 128;
  f32x4 acc[4][4] = {};
  for (int k0 = 0; k0 < 768; k0 += 64) {
    __syncthreads();
    #pragma unroll
    for (int j = 0; j < 4; ++j) {
      const int seg = wave * 4 + j;
      const int gr = seg * 8 + (lane >> 3), gc = (lane & 7) << 3;
      gld16(A + (m0 + gr) * 768 + k0 + gc, As + seg * 512);
      gld16(Bw + (n0 + gr) * 768 + k0 + gc, Bs + seg * 512);
    }
    __syncthreads();
    #pragma unroll
    for (int ks = 0; ks < 2; ++ks) {
      f16x8 af[4], bf[4];
      const int p = ((ks * 4 + hi) ^ (lo & 7)) << 3;
      #pragma unroll
      for (int t = 0; t < 4; ++t) {
        af[t] = *(const f16x8*)(As + (wm + t * 16 + lo) * 64 + p);
        bf[t] = *(const f16x8*)(Bs + (wn + t * 16 + lo) * 64 + p);
      }
      #pragma unroll
      for (int mt = 0; mt < 4; ++mt)
        #pragma unroll
        for (int nt = 0; nt < 4; ++nt)
          acc[mt][nt] = MFMA16(af[mt], bf[nt], acc[mt][nt]);
    }
  }
  // epilogue: C/D layout col=lane&15 (n), row=(lane>>4)*4+i (m)
  const int b = m0 >> 10;
  const int nrbase = (m0 & 1023) + wm;
  #pragma unroll
  for (int nt = 0; nt < 4; ++nt) {
    const int n = n0 + wn + nt * 16 + lo;
    if (n < 1728) {   // wave-uniform: 16-wide n-group never crosses a 576 boundary
      const float bv = bias[n];
      const int t3 = n / 576;
      const int rem = n - t3 * 576;
      const int hh = rem >> 6, d = rem & 63;
      const int bh16 = (b * 9 + hh) << 16;
      if (t3 == 2) {
        // V transposed + swizzled: element (d, t): chunk c=t>>3, pos=(c&~7)|((c^d)&7)
        _Float16* dv = Vt + bh16 + d * 1024;
        #pragma unroll
        for (int mt = 0; mt < 4; ++mt) {
          const int nr = nrbase + mt * 16 + hi * 4;
          const int c = nr >> 3;
          const int pos = (c & ~7) | ((c ^ d) & 7);
          union { f16x4 v; h16x2 h[2]; } u;
          u.h[0] = __builtin_amdgcn_cvt_pkrtz(acc[mt][nt][0] + bv, acc[mt][nt][1] + bv);
          u.h[1] = __builtin_amdgcn_cvt_pkrtz(acc[mt][nt][2] + bv, acc[mt][nt][3] + bv);
          *(f16x4*)(dv + pos * 8 + (nr & 7)) = u.v;
        }
      } else if (t3 == 1) {
        // K swizzled: element (t, d) at t*64 + ((d>>3 ^ (t&7))<<3) + (d&7)
        _Float16* dk = Ko + bh16;
        const int ch = d >> 3, dl = d & 7;
        #pragma unroll
        for (int mt = 0; mt < 4; ++mt) {
          const int nr = nrbase + mt * 16 + hi * 4;
          #pragma unroll
          for (int i = 0; i < 4; ++i) {
            const int t = nr + i;
            dk[t * 64 + ((ch ^ (t & 7)) << 3) + dl] = (_Float16)(acc[mt][nt][i] + bv);
          }
        }
      } else {
        _Float16* dq = Qo + bh16 + d;   // Q plain row-major
        #pragma unroll
        for (int mt = 0; mt < 4; ++mt) {
          const int nr = nrbase + mt * 16 + hi * 4;
          #pragma unroll
          for (int i = 0; i < 4; ++i)
            dq[(nr + i) * 64] = (_Float16)(acc[mt][nt][i] + bv);
        }
      }
    }
  }
}

// ---------------------------------------------------------------- flash attention (pipelined, 2 q-groups/wave)
// S^T = K·Q^T, O^T = V^T·P^T.  128 q rows/block (4 waves x 2 groups of 16 q),
// K-tile 64, double-buffered K/V, counted vmcnt(4) waits.
// K fragments read from LDS ONCE feed both q-groups' MFMAs; the two groups'
// softmax chains are independent -> in-wave ILP hides the serial chain.
// ZERO lambdas: rounds 2/3 proved that once the tile body exceeds clang's
// inline-cost threshold, [&]-capture lambdas get OUTLINED and every captured
// accumulator array becomes scratch (VGPR 64 + ~760MB scratch traffic).
// Everything below is textual macros in one function scope: inlining is
// guaranteed, all array indices compile-time constant, SROA cannot fail.
// LDS: Ks[2][64x64] 16KB + Vts[2][64x64] 16KB + Ps[4][16x64] 8KB = 40KB -> 4 blocks/CU.
// Ps is wave-private, reused sequentially by the two groups (in-order DS pipe, WAR safe).
// Grid 1152, XCD-major: 18 heads x 8 q-blocks per XCD -> K/V L2-resident.
__global__ __launch_bounds__(256, 4) void attn_fused(const _Float16* __restrict__ Qg,
                                                     const _Float16* __restrict__ Kg,
                                                     const _Float16* __restrict__ Vtg,
                                                     _Float16* __restrict__ Og) {
  __shared__ __align__(16) _Float16 Ks[2][64 * 64];
  __shared__ __align__(16) _Float16 Vts[2][64 * 64];
  __shared__ __align__(16) _Float16 Ps[4][16 * 64];
  const int tid = threadIdx.x;
  const int wave = tid >> 6, lane = tid & 63;
  const int lo = lane & 15, hi = lane >> 4;
  // XCD-major block mapping: bid%8 = XCD, 18 heads x 8 q-blocks per XCD
  const int bid = blockIdx.x;
  const int xcd = bid & 7, idx = bid >> 3;      // idx 0..143
  const int bh = xcd * 18 + (idx >> 3);         // 0..143
  const int q0 = (idx & 7) << 7;                // 0,128,...,896
  const _Float16* Qp  = Qg + (bh << 16);
  const _Float16* Kp  = Kg + (bh << 16);
  const _Float16* Vtp = Vtg + (bh << 16);

  // issue DMA for K/V tile starting at T0 into buffer NB (4 gld16/wave, 16/block)
  #define ISSUE(T0, NB) do {                                                        \
    _Pragma("unroll")                                                               \
    for (int j = 0; j < 2; ++j) {                                                   \
      const int seg = wave * 2 + j;                                                 \
      gld16(Kp + ((T0) + seg * 8 + (lane >> 3)) * 64 + ((lane & 7) << 3),           \
            &Ks[NB][seg * 512]);                                                    \
      gld16(Vtp + (seg * 8 + (lane >> 3)) * 1024 + (T0) + ((lane & 7) << 3),        \
            &Vts[NB][seg * 512]);                                                   \
    }                                                                               \
  } while (0)

  ISSUE(0, 0);   // prologue: tile 0 in flight

  // Q fragments straight from global: group g row = q0 + g*64 + wave*16 + lo
  f16x8 qf0[2], qf1[2];
  const _Float16* qrow0 = Qp + (q0 + wave * 16 + lo) * 64;
  const _Float16* qrow1 = qrow0 + 64 * 64;
  qf0[0] = *(const f16x8*)(qrow0 + hi * 8);
  qf0[1] = *(const f16x8*)(qrow0 + (4 + hi) * 8);
  qf1[0] = *(const f16x8*)(qrow1 + hi * 8);
  qf1[1] = *(const f16x8*)(qrow1 + (4 + hi) * 8);

  float m0_ = -1e30f, l0_ = 0.f, m1_ = -1e30f, l1_ = 0.f;
  f32x4 accO0[4] = {}, accO1[4] = {};
  const float cs = 0.125f * 1.44269504f;  // HD^-0.5 * log2(e)
  _Float16* Pw = Ps[wave];                // wave-private 16q x 64t, xor-swizzled

  // softmax + PV for one 16-q group. S/AO are array NAMES in this scope,
  // constant-indexed under unroll; MR/LR plain float lvalues. Vc in scope.
  #define GRP(S, AO, MR, LR) do {                                                   \
    float rmax = -1e30f;                                                            \
    _Pragma("unroll")                                                               \
    for (int tt = 0; tt < 4; ++tt)                                                  \
      rmax = fmaxf(rmax, fmaxf(fmaxf(S[tt][0], S[tt][1]), fmaxf(S[tt][2], S[tt][3])));\
    rmax = fmaxf(rmax, __shfl_xor(rmax, 16, 64));                                   \
    rmax = fmaxf(rmax, __shfl_xor(rmax, 32, 64));                                   \
    const float mnew = fmaxf(MR, rmax * cs);                                        \
    const float alpha = __builtin_amdgcn_exp2f(MR - mnew);                          \
    float rsum = 0.f;                                                               \
    _Pragma("unroll")                                                               \
    for (int tt = 0; tt < 4; ++tt) {                                                \
      const float p0 = __builtin_amdgcn_exp2f(fmaf(S[tt][0], cs, -mnew));           \
      const float p1 = __builtin_amdgcn_exp2f(fmaf(S[tt][1], cs, -mnew));           \
      const float p2 = __builtin_amdgcn_exp2f(fmaf(S[tt][2], cs, -mnew));           \
      const float p3 = __builtin_amdgcn_exp2f(fmaf(S[tt][3], cs, -mnew));           \
      rsum += (p0 + p1) + (p2 + p3);                                                \
      union { f16x4 v; h16x2 h[2]; } u;                                             \
      u.h[0] = __builtin_amdgcn_cvt_pkrtz(p0, p1);                                  \
      u.h[1] = __builtin_amdgcn_cvt_pkrtz(p2, p3);                                  \
      const int c = 2 * tt + (hi >> 1);                                             \
      *(f16x4*)(Pw + lo * 64 + (((c ^ lo) & 7) << 3) + ((hi & 1) << 2)) = u.v;      \
    }                                                                               \
    rsum += __shfl_xor(rsum, 16, 64);                                               \
    rsum += __shfl_xor(rsum, 32, 64);                                               \
    LR = LR * alpha + rsum;                                                         \
    MR = mnew;                                                                      \
    _Pragma("unroll")                                                               \
    for (int dt = 0; dt < 4; ++dt) AO[dt] *= alpha;                                 \
    _Pragma("unroll")                                                               \
    for (int ks2 = 0; ks2 < 2; ++ks2) {                                             \
      const int c = 4 * ks2 + hi;                                                   \
      const f16x8 pf = *(const f16x8*)(Pw + lo * 64 + (((c ^ lo) & 7) << 3));       \
      _Pragma("unroll")                                                             \
      for (int dt = 0; dt < 4; ++dt) {                                              \
        const int dd = dt * 16 + lo;                                                \
        const f16x8 vf = *(const f16x8*)(Vc + dd * 64 + (((c ^ dd) & 7) << 3));     \
        AO[dt] = MFMA16(vf, pf, AO[dt]);                                            \
      }                                                                             \
    }                                                                               \
  } while (0)

  // full tile compute on buffer CB: S^T both groups (K fragment read once), then GRP x2
  #define COMPUTE(CB) do {                                                          \
    const _Float16* Kc = Ks[CB];                                                    \
    const _Float16* Vc = Vts[CB];                                                   \
    f32x4 s0_[4] = {}, s1_[4] = {};                                                 \
    _Pragma("unroll")                                                               \
    for (int tt = 0; tt < 4; ++tt)                                                  \
      _Pragma("unroll")                                                             \
      for (int ks = 0; ks < 2; ++ks) {                                              \
        const f16x8 kf = *(const f16x8*)(Kc + (tt * 16 + lo) * 64 +                 \
                                         (((ks * 4 + hi) ^ (lo & 7)) << 3));        \
        s0_[tt] = MFMA16(kf, qf0[ks], s0_[tt]);                                     \
        s1_[tt] = MFMA16(kf, qf1[ks], s1_[tt]);                                     \
      }                                                                             \
    GRP(s0_, accO0, m0_, l0_);                                                      \
    GRP(s1_, accO1, m1_, l1_);                                                      \
  } while (0)

  // pipelined step: prefetch next tile into CB^1, counted wait, barrier, compute CB
  #define STEP_PRE(TN0, CB) do {                                                    \
    ISSUE(TN0, (CB) ^ 1);                                                           \
    asm volatile("s_waitcnt vmcnt(4)" ::: "memory");  /* tile CB landed */          \
    __builtin_amdgcn_sched_barrier(0);                                              \
    __builtin_amdgcn_s_barrier();       /* cross-wave: all tile-CB segs visible */  \
    COMPUTE(CB);                                                                    \
    __builtin_amdgcn_sched_barrier(0);                                              \
    __builtin_amdgcn_s_barrier();       /* reads of buf CB done before re-DMA */    \
  } while (0)

  #define STEP_LAST(CB) do {                                                        \
    asm volatile("s_waitcnt vmcnt(0)" ::: "memory");  /* final drain */             \
    __builtin_amdgcn_sched_barrier(0);                                              \
    __builtin_amdgcn_s_barrier();                                                   \
    COMPUTE(CB);                                                                    \
  } while (0)

  #pragma unroll 1
  for (int it = 0; it < 7; ++it) {      // tiles 0..13
    STEP_PRE((2 * it + 1) << 6, 0);
    STEP_PRE((2 * it + 2) << 6, 1);
  }
  STEP_PRE(15 << 6, 0);                 // tile 14, prefetch tile 15
  STEP_LAST(1);                         // tile 15, no prefetch

  // O^T C layout: col=lo=q, row=hi*4+i (+16*dt) = d. Write Oh [16384,576] swizzled.
  const int b = bh / 9, hh = bh - b * 9;
  {
    const float inv = 1.f / l0_;
    const int rq = (b << 10) + q0 + wave * 16 + lo;
    #pragma unroll
    for (int dt = 0; dt < 4; ++dt) {
      union { f16x4 v; h16x2 h[2]; } u;
      u.h[0] = __builtin_amdgcn_cvt_pkrtz(accO0[dt][0] * inv, accO0[dt][1] * inv);
      u.h[1] = __builtin_amdgcn_cvt_pkrtz(accO0[dt][2] * inv, accO0[dt][3] * inv);
      const int c = hh * 8 + dt * 2 + (hi >> 1);
      const int pos = (c & ~7) | ((c ^ rq) & 7);
      *(f16x4*)(Og + rq * 576 + pos * 8 + ((hi & 1) << 2)) = u.v;
    }
  }
  {
    const float inv = 1.f / l1_;
    const int rq = (b << 10) + q0 + 64 + wave * 16 + lo;
    #pragma unroll
    for (int dt = 0; dt < 4; ++dt) {
      union { f16x4 v; h16x2 h[2]; } u;
      u.h[0] = __builtin_amdgcn_cvt_pkrtz(accO1[dt][0] * inv, accO1[dt][1] * inv);
      u.h[1] = __builtin_amdgcn_cvt_pkrtz(accO1[dt][2] * inv, accO1[dt][3] * inv);
      const int c = hh * 8 + dt * 2 + (hi >> 1);
      const int pos = (c & ~7) | ((c ^ rq) & 7);
      *(f16x4*)(Og + rq * 576 + pos * 8 + ((hi & 1) << 2)) = u.v;
    }
  }
  #undef STEP_LAST
  #undef STEP_PRE
  #undef COMPUTE
  #undef GRP
  #undef ISSUE
}

// ---------------------------------------------------------------- GEMM3: out = O @ proj_w^T + b (fp32 out)
__global__ __launch_bounds__(256, 4) void gemm3_proj(const _Float16* __restrict__ A,
                                                     const _Float16* __restrict__ Bw,
                                                     const float* __restrict__ bias,
                                                     float* __restrict__ out) {
  __shared__ __align__(16) _Float16 As[128 * 64];
  __shared__ __align__(16) _Float16 Bs[128 * 64];
  const int tid = threadIdx.x;
  const int wave = tid >> 6, lane = tid & 63;
  const int lo = lane & 15, hi = lane >> 4;
  const int wm = (wave >> 1) * 64, wn = (wave & 1) * 64;
  const int m0 = blockIdx.x * 128, n0 = blockIdx.y * 128;
  f32x4 acc[4][4] = {};
  for (int k0 = 0; k0 < 576; k0 += 64) {
    __syncthreads();
    #pragma unroll
    for (int j = 0; j < 4; ++j) {
      const int seg = wave * 4 + j;
      const int gr = seg * 8 + (lane >> 3), gc = (lane & 7) << 3;
      gld16(A + (m0 + gr) * 576 + k0 + gc, As + seg * 512);
      gld16(Bw + (n0 + gr) * 576 + k0 + gc, Bs + seg * 512);
    }
    __syncthreads();
    #pragma unroll
    for (int ks = 0; ks < 2; ++ks) {
      f16x8 af[4], bf[4];
      const int p = ((ks * 4 + hi) ^ (lo & 7)) << 3;
      #pragma unroll
      for (int t = 0; t < 4; ++t) {
        af[t] = *(const f16x8*)(As + (wm + t * 16 + lo) * 64 + p);
        bf[t] = *(const f16x8*)(Bs + (wn + t * 16 + lo) * 64 + p);
      }
      #pragma unroll
      for (int mt = 0; mt < 4; ++mt)
        #pragma unroll
        for (int nt = 0; nt < 4; ++nt)
          acc[mt][nt] = MFMA16(af[mt], bf[nt], acc[mt][nt]);
    }
  }
  #pragma unroll
  for (int nt = 0; nt < 4; ++nt) {
    const int n = n0 + wn + nt * 16 + lo;
    const float bv = bias[n];
    #pragma unroll
    for (int mt = 0; mt < 4; ++mt) {
      const int mrow = m0 + wm + mt * 16 + hi * 4;
      #pragma unroll
      for (int i = 0; i < 4; ++i)
        out[(mrow + i) * 768 + n] = acc[mt][nt][i] + bv;
    }
  }
}

// ---------------------------------------------------------------- launch
extern "C" void kernel_launch(void* const* d_in, const int* in_sizes, int n_in,
                              void* d_out, int out_size, void* d_ws, size_t ws_size,
                              hipStream_t stream) {
  const float* x      = (const float*)d_in[0];
  const float* qkv_w  = (const float*)d_in[1];
  const float* qkv_b  = (const float*)d_in[2];
  const float* proj_w = (const float*)d_in[3];
  const float* proj_b = (const float*)d_in[4];
  float* out = (float*)d_out;

  char* ws = (char*)d_ws;
  _Float16* x16 = (_Float16*)(ws + 0);          // 16384*768*2  swz
  _Float16* w1p = (_Float16*)(ws + 25165824);   // 1792*768*2   swz, rows>=1728 zero
  _Float16* w2h = (_Float16*)(ws + 27918336);   // 768*576*2    swz
  _Float16* Qh  = (_Float16*)(ws + 28803072);   // [bh][1024][64] plain
  _Float16* Kh  = (_Float16*)(ws + 47677440);   // [bh][1024][64] swz
  _Float16* Vth = (_Float16*)(ws + 66551808);   // [bh][64][1024] transposed swz
  _Float16* Oh  = (_Float16*)(ws + 85426176);   // [16384][576] swz

  cvt_swz<<<6144, 256, 0, stream>>>(x, x16, 16384, 96, 16384 * 96);
  cvt_swz<<<672, 256, 0, stream>>>(qkv_w, w1p, 1728, 96, 1792 * 96);
  cvt_swz<<<216, 256, 0, stream>>>(proj_w, w2h, 768, 72, 768 * 72);
  gemm1_qkv<<<dim3(128, 14), 256, 0, stream>>>(x16, w1p, qkv_b, Qh, Kh, Vth);
  attn_fused<<<1152, 256, 0, stream>>>(Qh, Kh, Vth, Oh);
  gemm3_proj<<<dim3(128, 6), 256, 0, stream>>>(Oh, w2h, proj_b, out);
}

// Round 5
// 247.395 us; speedup vs baseline: 1.6996x; 1.6996x over previous
//
#include <hip/hip_runtime.h>

// PrunedMultiHeadAttention: B=16,N=1024,C=768,H=9,HD=64
// All f16 operand matrices live in global memory XOR-chunk-swizzled:
//   within each aligned group of 8 16B-chunks (64 elems = one BK tile),
//   logical chunk c of row r is stored at position (c & ~7) | ((c ^ r) & 7).
// This makes global_load_lds (lane-linear DMA into unpadded stride-64/128 LDS)
// conflict-free on the MFMA b128 fragment reads (group = (4ks+hi)^(lo&7)).

typedef _Float16 f16x8 __attribute__((ext_vector_type(8)));
typedef _Float16 f16x4 __attribute__((ext_vector_type(4)));
typedef __fp16   h16x2 __attribute__((ext_vector_type(2)));  // cvt_pkrtz result type
typedef float    f32x4 __attribute__((ext_vector_type(4)));

#define MFMA16(a, b, c) __builtin_amdgcn_mfma_f32_16x16x32_f16(a, b, c, 0, 0, 0)

// async global->LDS DMA, 16B/lane; LDS dest = wave-uniform base + lane*16
__device__ __forceinline__ void gld16(const _Float16* g, _Float16* l) {
  __builtin_amdgcn_global_load_lds((const __attribute__((address_space(1))) void*)g,
                                   (__attribute__((address_space(3))) void*)l, 16, 0, 0);
}

// ---------------------------------------------------------------- convert + swizzle
// fp32 row-major [rows_src x (cpr*8)] -> fp16 swizzled [rows_dst x (cpr*8)], zero-pad rows >= rows_src
__global__ __launch_bounds__(256) void cvt_swz(const float* __restrict__ src,
                                               _Float16* __restrict__ dst,
                                               int rows_src, int cpr, int total) {
  const int g = blockIdx.x * 256 + threadIdx.x;
  if (g >= total) return;
  const int row = g / cpr;
  const int c = g - row * cpr;
  const int L = cpr * 8;
  const int pos = (c & ~7) | ((c ^ row) & 7);
  union { f16x8 v; h16x2 h[4]; } u;
  if (row < rows_src) {
    const float4 a = *(const float4*)(src + row * L + c * 8);
    const float4 b = *(const float4*)(src + row * L + c * 8 + 4);
    u.h[0] = __builtin_amdgcn_cvt_pkrtz(a.x, a.y);
    u.h[1] = __builtin_amdgcn_cvt_pkrtz(a.z, a.w);
    u.h[2] = __builtin_amdgcn_cvt_pkrtz(b.x, b.y);
    u.h[3] = __builtin_amdgcn_cvt_pkrtz(b.z, b.w);
  } else {
    u.v = (f16x8){};
  }
  *(f16x8*)(dst + row * L + pos * 8) = u.v;
}

// ---------------------------------------------------------------- GEMM1: qkv = x @ W^T + b
// A: x16 swz [16384,768], Bw: w1 swz padded [1792,768] (rows >=1728 zero)
// Q -> [B,H,N,64] plain; K -> [B,H,N,64] swizzled; V -> [B,H,64,N] transposed+swizzled
// 1-D grid 1792 = 8 XCD x 16 m-tiles x 14 n-tiles, n-inner: each 196KB A-panel
// stays L2-hot for 14 consecutive same-XCD blocks; full B (2.65MB) L2-resident/XCD.
__global__ __launch_bounds__(256, 4) void gemm1_qkv(const _Float16* __restrict__ A,
                                                    const _Float16* __restrict__ Bw,
                                                    const float* __restrict__ bias,
                                                    _Float16* __restrict__ Qo,
                                                    _Float16* __restrict__ Ko,
                                                    _Float16* __restrict__ Vt) {
  __shared__ __align__(16) _Float16 As[128 * 64];
  __shared__ __align__(16) _Float16 Bs[128 * 64];
  const int tid = threadIdx.x;
  const int wave = tid >> 6, lane = tid & 63;
  const int lo = lane & 15, hi = lane >> 4;
  const int wm = (wave >> 1) * 64, wn = (wave & 1) * 64;
  const int g = blockIdx.x;
  const int xcd = g & 7, i = g >> 3;            // i in [0,224)
  const int mt = i / 14, ntl = i - mt * 14;     // 16 m-tiles/XCD, 14 n-tiles
  const int m0 = (xcd * 16 + mt) * 128, n0 = ntl * 128;
  f32x4 acc[4][4] = {};
  for (int k0 = 0; k0 < 768; k0 += 64) {
    __syncthreads();
    #pragma unroll
    for (int j = 0; j < 4; ++j) {
      const int seg = wave * 4 + j;
      const int gr = seg * 8 + (lane >> 3), gc = (lane & 7) << 3;
      gld16(A + (m0 + gr) * 768 + k0 + gc, As + seg * 512);
      gld16(Bw + (n0 + gr) * 768 + k0 + gc, Bs + seg * 512);
    }
    __syncthreads();
    #pragma unroll
    for (int ks = 0; ks < 2; ++ks) {
      f16x8 af[4], bf[4];
      const int p = ((ks * 4 + hi) ^ (lo & 7)) << 3;
      #pragma unroll
      for (int t = 0; t < 4; ++t) {
        af[t] = *(const f16x8*)(As + (wm + t * 16 + lo) * 64 + p);
        bf[t] = *(const f16x8*)(Bs + (wn + t * 16 + lo) * 64 + p);
      }
      #pragma unroll
      for (int mt2 = 0; mt2 < 4; ++mt2)
        #pragma unroll
        for (int nt = 0; nt < 4; ++nt)
          acc[mt2][nt] = MFMA16(af[mt2], bf[nt], acc[mt2][nt]);
    }
  }
  // epilogue: C/D layout col=lane&15 (n), row=(lane>>4)*4+i (m)
  const int b = m0 >> 10;
  const int nrbase = (m0 & 1023) + wm;
  #pragma unroll
  for (int nt = 0; nt < 4; ++nt) {
    const int n = n0 + wn + nt * 16 + lo;
    if (n < 1728) {   // wave-uniform: 16-wide n-group never crosses a 576 boundary
      const float bv = bias[n];
      const int t3 = n / 576;
      const int rem = n - t3 * 576;
      const int hh = rem >> 6, d = rem & 63;
      const int bh16 = (b * 9 + hh) << 16;
      if (t3 == 2) {
        // V transposed + swizzled: element (d, t): chunk c=t>>3, pos=(c&~7)|((c^d)&7)
        _Float16* dv = Vt + bh16 + d * 1024;
        #pragma unroll
        for (int mt2 = 0; mt2 < 4; ++mt2) {
          const int nr = nrbase + mt2 * 16 + hi * 4;
          const int c = nr >> 3;
          const int pos = (c & ~7) | ((c ^ d) & 7);
          union { f16x4 v; h16x2 h[2]; } u;
          u.h[0] = __builtin_amdgcn_cvt_pkrtz(acc[mt2][nt][0] + bv, acc[mt2][nt][1] + bv);
          u.h[1] = __builtin_amdgcn_cvt_pkrtz(acc[mt2][nt][2] + bv, acc[mt2][nt][3] + bv);
          *(f16x4*)(dv + pos * 8 + (nr & 7)) = u.v;
        }
      } else if (t3 == 1) {
        // K swizzled: element (t, d) at t*64 + ((d>>3 ^ (t&7))<<3) + (d&7)
        _Float16* dk = Ko + bh16;
        const int ch = d >> 3, dl = d & 7;
        #pragma unroll
        for (int mt2 = 0; mt2 < 4; ++mt2) {
          const int nr = nrbase + mt2 * 16 + hi * 4;
          #pragma unroll
          for (int i2 = 0; i2 < 4; ++i2) {
            const int t = nr + i2;
            dk[t * 64 + ((ch ^ (t & 7)) << 3) + dl] = (_Float16)(acc[mt2][nt][i2] + bv);
          }
        }
      } else {
        _Float16* dq = Qo + bh16 + d;   // Q plain row-major
        #pragma unroll
        for (int mt2 = 0; mt2 < 4; ++mt2) {
          const int nr = nrbase + mt2 * 16 + hi * 4;
          #pragma unroll
          for (int i2 = 0; i2 < 4; ++i2)
            dq[(nr + i2) * 64] = (_Float16)(acc[mt2][nt][i2] + bv);
        }
      }
    }
  }
}

// ---------------------------------------------------------------- flash attention (pipelined)
// S^T = K·Q^T, O^T = V^T·P^T.  64 q rows/block, K-tile 64, double-buffered K/V,
// counted vmcnt(4) waits (loads for tile t+1 stay in flight across the barrier).
// LDS: Ks[2][64x64] 16KB + Vts[2][64x64] 16KB + Ps[4][16x64] 8KB = 40KB -> 4 blocks/CU.
// Q is consumed directly from global (16B/lane fragment loads) - never staged.
// Grid is 1-D 2304 with XCD-major mapping: all 16 q-blocks of a head on one XCD
// so K/V (256KB/head) are L2-resident.
// Round-1-verified structure (78.7us, VGPR 56); only addition: T13 defer-max.
__global__ __launch_bounds__(256, 4) void attn_fused(const _Float16* __restrict__ Qg,
                                                     const _Float16* __restrict__ Kg,
                                                     const _Float16* __restrict__ Vtg,
                                                     _Float16* __restrict__ Og) {
  __shared__ __align__(16) _Float16 Ks[2][64 * 64];
  __shared__ __align__(16) _Float16 Vts[2][64 * 64];
  __shared__ __align__(16) _Float16 Ps[4][16 * 64];
  const int tid = threadIdx.x;
  const int wave = tid >> 6, lane = tid & 63;
  const int lo = lane & 15, hi = lane >> 4;
  // XCD-major block mapping: bid%8 = XCD, 18 heads per XCD, 16 q-blocks per head
  const int bid = blockIdx.x;
  const int xcd = bid & 7, idx = bid >> 3;      // idx 0..287
  const int bh = xcd * 18 + (idx >> 4);         // 0..143
  const int q0 = (idx & 15) << 6;
  const _Float16* Qp  = Qg + (bh << 16);
  const _Float16* Kp  = Kg + (bh << 16);
  const _Float16* Vtp = Vtg + (bh << 16);

  // issue DMA for K/V tile starting at t0 into buffer nb (4 gld16/wave, 16/block)
  auto issue = [&](int t0, int nb) {
    #pragma unroll
    for (int j = 0; j < 2; ++j) {
      const int seg = wave * 2 + j;
      gld16(Kp + (t0 + seg * 8 + (lane >> 3)) * 64 + ((lane & 7) << 3), &Ks[nb][seg * 512]);
      gld16(Vtp + (seg * 8 + (lane >> 3)) * 1024 + t0 + ((lane & 7) << 3), &Vts[nb][seg * 512]);
    }
  };

  issue(0, 0);   // prologue: tile 0 in flight

  // Q fragment straight from global: lane needs Q[q0+wave*16+lo][ (ks*4+hi)*8 .. +7 ]
  f16x8 qf[2];
  const _Float16* qrow = Qp + (q0 + wave * 16 + lo) * 64;
  qf[0] = *(const f16x8*)(qrow + hi * 8);
  qf[1] = *(const f16x8*)(qrow + (4 + hi) * 8);

  float m_run = -1e30f, l_run = 0.f;
  f32x4 accO[4] = {};
  const float cs = 0.125f * 1.44269504f;  // HD^-0.5 * log2(e)
  _Float16* Pw = Ps[wave];                // wave-private 16q x 64t, xor-swizzled

  auto compute = [&](int cb) {
    const _Float16* Kc = Ks[cb];
    const _Float16* Vc = Vts[cb];
    // S^T: C layout col=lo=q, row=hi*4+i (+16*tt) = t
    f32x4 sacc[4] = {};
    #pragma unroll
    for (int tt = 0; tt < 4; ++tt)
      #pragma unroll
      for (int ks = 0; ks < 2; ++ks) {
        const f16x8 kf = *(const f16x8*)(Kc + (tt * 16 + lo) * 64 + (((ks * 4 + hi) ^ (lo & 7)) << 3));
        sacc[tt] = MFMA16(kf, qf[ks], sacc[tt]);
      }
    float rmax = -1e30f;
    #pragma unroll
    for (int tt = 0; tt < 4; ++tt)
      rmax = fmaxf(rmax, fmaxf(fmaxf(sacc[tt][0], sacc[tt][1]), fmaxf(sacc[tt][2], sacc[tt][3])));
    rmax = fmaxf(rmax, __shfl_xor(rmax, 16, 64));
    rmax = fmaxf(rmax, __shfl_xor(rmax, 32, 64));
    // T13 defer-max: if no row's max grew by >8 (wave-uniform check), keep m_run;
    // P is then bounded by 2^8 (fine in f16) and the alpha-rescale is skipped.
    const float rs = rmax * cs;
    const bool nsk = !__all(rs <= m_run + 8.f);
    const float mnew = nsk ? fmaxf(m_run, rs) : m_run;
    const float alpha = nsk ? __builtin_amdgcn_exp2f(m_run - mnew) : 1.f;
    float rsum = 0.f;
    #pragma unroll
    for (int tt = 0; tt < 4; ++tt) {
      const float p0 = __builtin_amdgcn_exp2f(fmaf(sacc[tt][0], cs, -mnew));
      const float p1 = __builtin_amdgcn_exp2f(fmaf(sacc[tt][1], cs, -mnew));
      const float p2 = __builtin_amdgcn_exp2f(fmaf(sacc[tt][2], cs, -mnew));
      const float p3 = __builtin_amdgcn_exp2f(fmaf(sacc[tt][3], cs, -mnew));
      rsum += (p0 + p1) + (p2 + p3);
      union { f16x4 v; h16x2 h[2]; } u;
      u.h[0] = __builtin_amdgcn_cvt_pkrtz(p0, p1);
      u.h[1] = __builtin_amdgcn_cvt_pkrtz(p2, p3);
      const int c = 2 * tt + (hi >> 1);
      *(f16x4*)(Pw + lo * 64 + (((c ^ lo) & 7) << 3) + ((hi & 1) << 2)) = u.v;
    }
    rsum += __shfl_xor(rsum, 16, 64);
    rsum += __shfl_xor(rsum, 32, 64);
    l_run = l_run * alpha + rsum;
    m_run = mnew;
    if (nsk) {
      #pragma unroll
      for (int dt = 0; dt < 4; ++dt) accO[dt] *= alpha;
    }

    // O^T += V^T · P^T (Pw wave-private: no barrier before reads)
    #pragma unroll
    for (int ks2 = 0; ks2 < 2; ++ks2) {
      const int c = 4 * ks2 + hi;
      const f16x8 pf = *(const f16x8*)(Pw + lo * 64 + (((c ^ lo) & 7) << 3));
      #pragma unroll
      for (int dt = 0; dt < 4; ++dt) {
        const int dd = dt * 16 + lo;
        const f16x8 vf = *(const f16x8*)(Vc + dd * 64 + (((c ^ dd) & 7) << 3));
        accO[dt] = MFMA16(vf, pf, accO[dt]);
      }
    }
  };

  // one pipelined step: prefetch next tile, counted wait for current, compute
  auto step = [&](int tnext0, int cb, bool pre) {
    if (pre) {
      issue(tnext0, cb ^ 1);
      asm volatile("s_waitcnt vmcnt(4)" ::: "memory");   // tile cb landed; next stays in flight
    } else {
      asm volatile("s_waitcnt vmcnt(0)" ::: "memory");   // last tile: full drain
    }
    __builtin_amdgcn_sched_barrier(0);
    __builtin_amdgcn_s_barrier();       // cross-wave: all tile-cb segments visible
    compute(cb);
    __builtin_amdgcn_sched_barrier(0);
    __builtin_amdgcn_s_barrier();       // all reads of buf cb done before it is re-DMA'd
  };

  #pragma unroll 1
  for (int it = 0; it < 7; ++it) {      // tiles 0..13
    step((2 * it + 1) << 6, 0, true);
    step((2 * it + 2) << 6, 1, true);
  }
  step(15 << 6, 0, true);               // tile 14, prefetch tile 15
  step(0, 1, false);                    // tile 15, no prefetch

  // O^T C layout: col=lo=q, row=hi*4+i (+16*dt) = d. Write Oh [16384,576] swizzled.
  const float inv = 1.f / l_run;
  const int b = bh / 9, hh = bh - b * 9;
  const int rq = (b << 10) + q0 + wave * 16 + lo;
  #pragma unroll
  for (int dt = 0; dt < 4; ++dt) {
    union { f16x4 v; h16x2 h[2]; } u;
    u.h[0] = __builtin_amdgcn_cvt_pkrtz(accO[dt][0] * inv, accO[dt][1] * inv);
    u.h[1] = __builtin_amdgcn_cvt_pkrtz(accO[dt][2] * inv, accO[dt][3] * inv);
    const int c = hh * 8 + dt * 2 + (hi >> 1);
    const int pos = (c & ~7) | ((c ^ rq) & 7);
    *(f16x4*)(Og + rq * 576 + pos * 8 + ((hi & 1) << 2)) = u.v;
  }
}

// ---------------------------------------------------------------- GEMM3: out = O @ proj_w^T + b (fp32 out)
// 1-D grid 768 = 8 XCD x 16 m-tiles x 6 n-tiles, n-inner: A-panel L2-hot per XCD.
__global__ __launch_bounds__(256, 4) void gemm3_proj(const _Float16* __restrict__ A,
                                                     const _Float16* __restrict__ Bw,
                                                     const float* __restrict__ bias,
                                                     float* __restrict__ out) {
  __shared__ __align__(16) _Float16 As[128 * 64];
  __shared__ __align__(16) _Float16 Bs[128 * 64];
  const int tid = threadIdx.x;
  const int wave = tid >> 6, lane = tid & 63;
  const int lo = lane & 15, hi = lane >> 4;
  const int wm = (wave >> 1) * 64, wn = (wave & 1) * 64;
  const int g = blockIdx.x;
  const int xcd = g & 7, i = g >> 3;            // i in [0,96)
  const int mt = i / 6, ntl = i - mt * 6;       // 16 m-tiles/XCD, 6 n-tiles
  const int m0 = (xcd * 16 + mt) * 128, n0 = ntl * 128;
  f32x4 acc[4][4] = {};
  for (int k0 = 0; k0 < 576; k0 += 64) {
    __syncthreads();
    #pragma unroll
    for (int j = 0; j < 4; ++j) {
      const int seg = wave * 4 + j;
      const int gr = seg * 8 + (lane >> 3), gc = (lane & 7) << 3;
      gld16(A + (m0 + gr) * 576 + k0 + gc, As + seg * 512);
      gld16(Bw + (n0 + gr) * 576 + k0 + gc, Bs + seg * 512);
    }
    __syncthreads();
    #pragma unroll
    for (int ks = 0; ks < 2; ++ks) {
      f16x8 af[4], bf[4];
      const int p = ((ks * 4 + hi) ^ (lo & 7)) << 3;
      #pragma unroll
      for (int t = 0; t < 4; ++t) {
        af[t] = *(const f16x8*)(As + (wm + t * 16 + lo) * 64 + p);
        bf[t] = *(const f16x8*)(Bs + (wn + t * 16 + lo) * 64 + p);
      }
      #pragma unroll
      for (int mt2 = 0; mt2 < 4; ++mt2)
        #pragma unroll
        for (int nt = 0; nt < 4; ++nt)
          acc[mt2][nt] = MFMA16(af[mt2], bf[nt], acc[mt2][nt]);
    }
  }
  #pragma unroll
  for (int nt = 0; nt < 4; ++nt) {
    const int n = n0 + wn + nt * 16 + lo;
    const float bv = bias[n];
    #pragma unroll
    for (int mt2 = 0; mt2 < 4; ++mt2) {
      const int mrow = m0 + wm + mt2 * 16 + hi * 4;
      #pragma unroll
      for (int i2 = 0; i2 < 4; ++i2)
        out[(mrow + i2) * 768 + n] = acc[mt2][nt][i2] + bv;
    }
  }
}

// ---------------------------------------------------------------- launch
extern "C" void kernel_launch(void* const* d_in, const int* in_sizes, int n_in,
                              void* d_out, int out_size, void* d_ws, size_t ws_size,
                              hipStream_t stream) {
  const float* x      = (const float*)d_in[0];
  const float* qkv_w  = (const float*)d_in[1];
  const float* qkv_b  = (const float*)d_in[2];
  const float* proj_w = (const float*)d_in[3];
  const float* proj_b = (const float*)d_in[4];
  float* out = (float*)d_out;

  char* ws = (char*)d_ws;
  _Float16* x16 = (_Float16*)(ws + 0);          // 16384*768*2  swz
  _Float16* w1p = (_Float16*)(ws + 25165824);   // 1792*768*2   swz, rows>=1728 zero
  _Float16* w2h = (_Float16*)(ws + 27918336);   // 768*576*2    swz
  _Float16* Qh  = (_Float16*)(ws + 28803072);   // [bh][1024][64] plain
  _Float16* Kh  = (_Float16*)(ws + 47677440);   // [bh][1024][64] swz
  _Float16* Vth = (_Float16*)(ws + 66551808);   // [bh][64][1024] transposed swz
  _Float16* Oh  = (_Float16*)(ws + 85426176);   // [16384][576] swz

  cvt_swz<<<6144, 256, 0, stream>>>(x, x16, 16384, 96, 16384 * 96);
  cvt_swz<<<672, 256, 0, stream>>>(qkv_w, w1p, 1728, 96, 1792 * 96);
  cvt_swz<<<216, 256, 0, stream>>>(proj_w, w2h, 768, 72, 768 * 72);
  gemm1_qkv<<<1792, 256, 0, stream>>>(x16, w1p, qkv_b, Qh, Kh, Vth);
  attn_fused<<<2304, 256, 0, stream>>>(Qh, Kh, Vth, Oh);
  gemm3_proj<<<768, 256, 0, stream>>>(Oh, w2h, proj_b, out);
}

// Round 6
// 244.416 us; speedup vs baseline: 1.7203x; 1.0122x over previous
//
#include <hip/hip_runtime.h>

// PrunedMultiHeadAttention: B=16,N=1024,C=768,H=9,HD=64
// All f16 operand matrices live in global memory XOR-chunk-swizzled:
//   within each aligned group of 8 16B-chunks (64 elems = one BK tile),
//   logical chunk c of row r is stored at position (c & ~7) | ((c ^ r) & 7).
// This makes global_load_lds (lane-linear DMA into unpadded stride-64/128 LDS)
// conflict-free on the MFMA b128 fragment reads (group = (4ks+hi)^(lo&7)).

typedef _Float16 f16x8 __attribute__((ext_vector_type(8)));
typedef _Float16 f16x4 __attribute__((ext_vector_type(4)));
typedef __fp16   h16x2 __attribute__((ext_vector_type(2)));  // cvt_pkrtz result type
typedef float    f32x4 __attribute__((ext_vector_type(4)));

#define MFMA16(a, b, c) __builtin_amdgcn_mfma_f32_16x16x32_f16(a, b, c, 0, 0, 0)

// async global->LDS DMA, 16B/lane; LDS dest = wave-uniform base + lane*16
__device__ __forceinline__ void gld16(const _Float16* g, _Float16* l) {
  __builtin_amdgcn_global_load_lds((const __attribute__((address_space(1))) void*)g,
                                   (__attribute__((address_space(3))) void*)l, 16, 0, 0);
}

// ---------------------------------------------------------------- convert + swizzle
// fp32 row-major [rows_src x (cpr*8)] -> fp16 swizzled [rows_dst x (cpr*8)], zero-pad rows >= rows_src
__global__ __launch_bounds__(256) void cvt_swz(const float* __restrict__ src,
                                               _Float16* __restrict__ dst,
                                               int rows_src, int cpr, int total) {
  const int g = blockIdx.x * 256 + threadIdx.x;
  if (g >= total) return;
  const int row = g / cpr;
  const int c = g - row * cpr;
  const int L = cpr * 8;
  const int pos = (c & ~7) | ((c ^ row) & 7);
  union { f16x8 v; h16x2 h[4]; } u;
  if (row < rows_src) {
    const float4 a = *(const float4*)(src + row * L + c * 8);
    const float4 b = *(const float4*)(src + row * L + c * 8 + 4);
    u.h[0] = __builtin_amdgcn_cvt_pkrtz(a.x, a.y);
    u.h[1] = __builtin_amdgcn_cvt_pkrtz(a.z, a.w);
    u.h[2] = __builtin_amdgcn_cvt_pkrtz(b.x, b.y);
    u.h[3] = __builtin_amdgcn_cvt_pkrtz(b.z, b.w);
  } else {
    u.v = (f16x8){};
  }
  *(f16x8*)(dst + row * L + pos * 8) = u.v;
}

// ---------------------------------------------------------------- GEMM1: qkv = x @ W^T + b
// A: x16 swz [16384,768], Bw: w1 swz padded [1792,768] (rows >=1728 zero)
// Q -> [B,H,N,64] plain; K -> [B,H,N,64] swizzled; V -> [B,H,64,N] transposed+swizzled
// 1-D grid 1792 = 8 XCD x 16 m-tiles x 14 n-tiles, n-inner: each 196KB A-panel
// stays L2-hot for 14 consecutive same-XCD blocks; full B (2.65MB) L2-resident/XCD.
__global__ __launch_bounds__(256, 4) void gemm1_qkv(const _Float16* __restrict__ A,
                                                    const _Float16* __restrict__ Bw,
                                                    const float* __restrict__ bias,
                                                    _Float16* __restrict__ Qo,
                                                    _Float16* __restrict__ Ko,
                                                    _Float16* __restrict__ Vt) {
  __shared__ __align__(16) _Float16 As[128 * 64];
  __shared__ __align__(16) _Float16 Bs[128 * 64];
  const int tid = threadIdx.x;
  const int wave = tid >> 6, lane = tid & 63;
  const int lo = lane & 15, hi = lane >> 4;
  const int wm = (wave >> 1) * 64, wn = (wave & 1) * 64;
  const int g = blockIdx.x;
  const int xcd = g & 7, i = g >> 3;            // i in [0,224)
  const int mt = i / 14, ntl = i - mt * 14;     // 16 m-tiles/XCD, 14 n-tiles
  const int m0 = (xcd * 16 + mt) * 128, n0 = ntl * 128;
  f32x4 acc[4][4] = {};
  for (int k0 = 0; k0 < 768; k0 += 64) {
    __syncthreads();
    #pragma unroll
    for (int j = 0; j < 4; ++j) {
      const int seg = wave * 4 + j;
      const int gr = seg * 8 + (lane >> 3), gc = (lane & 7) << 3;
      gld16(A + (m0 + gr) * 768 + k0 + gc, As + seg * 512);
      gld16(Bw + (n0 + gr) * 768 + k0 + gc, Bs + seg * 512);
    }
    __syncthreads();
    #pragma unroll
    for (int ks = 0; ks < 2; ++ks) {
      f16x8 af[4], bf[4];
      const int p = ((ks * 4 + hi) ^ (lo & 7)) << 3;
      #pragma unroll
      for (int t = 0; t < 4; ++t) {
        af[t] = *(const f16x8*)(As + (wm + t * 16 + lo) * 64 + p);
        bf[t] = *(const f16x8*)(Bs + (wn + t * 16 + lo) * 64 + p);
      }
      #pragma unroll
      for (int mt2 = 0; mt2 < 4; ++mt2)
        #pragma unroll
        for (int nt = 0; nt < 4; ++nt)
          acc[mt2][nt] = MFMA16(af[mt2], bf[nt], acc[mt2][nt]);
    }
  }
  // epilogue: C/D layout col=lane&15 (n), row=(lane>>4)*4+i (m)
  const int b = m0 >> 10;
  const int nrbase = (m0 & 1023) + wm;
  #pragma unroll
  for (int nt = 0; nt < 4; ++nt) {
    const int n = n0 + wn + nt * 16 + lo;
    if (n < 1728) {   // wave-uniform: 16-wide n-group never crosses a 576 boundary
      const float bv = bias[n];
      const int t3 = n / 576;
      const int rem = n - t3 * 576;
      const int hh = rem >> 6, d = rem & 63;
      const int bh16 = (b * 9 + hh) << 16;
      if (t3 == 2) {
        // V transposed + swizzled: element (d, t): chunk c=t>>3, pos=(c&~7)|((c^d)&7)
        _Float16* dv = Vt + bh16 + d * 1024;
        #pragma unroll
        for (int mt2 = 0; mt2 < 4; ++mt2) {
          const int nr = nrbase + mt2 * 16 + hi * 4;
          const int c = nr >> 3;
          const int pos = (c & ~7) | ((c ^ d) & 7);
          union { f16x4 v; h16x2 h[2]; } u;
          u.h[0] = __builtin_amdgcn_cvt_pkrtz(acc[mt2][nt][0] + bv, acc[mt2][nt][1] + bv);
          u.h[1] = __builtin_amdgcn_cvt_pkrtz(acc[mt2][nt][2] + bv, acc[mt2][nt][3] + bv);
          *(f16x4*)(dv + pos * 8 + (nr & 7)) = u.v;
        }
      } else if (t3 == 1) {
        // K swizzled: element (t, d) at t*64 + ((d>>3 ^ (t&7))<<3) + (d&7)
        _Float16* dk = Ko + bh16;
        const int ch = d >> 3, dl = d & 7;
        #pragma unroll
        for (int mt2 = 0; mt2 < 4; ++mt2) {
          const int nr = nrbase + mt2 * 16 + hi * 4;
          #pragma unroll
          for (int i2 = 0; i2 < 4; ++i2) {
            const int t = nr + i2;
            dk[t * 64 + ((ch ^ (t & 7)) << 3) + dl] = (_Float16)(acc[mt2][nt][i2] + bv);
          }
        }
      } else {
        _Float16* dq = Qo + bh16 + d;   // Q plain row-major
        #pragma unroll
        for (int mt2 = 0; mt2 < 4; ++mt2) {
          const int nr = nrbase + mt2 * 16 + hi * 4;
          #pragma unroll
          for (int i2 = 0; i2 < 4; ++i2)
            dq[(nr + i2) * 64] = (_Float16)(acc[mt2][nt][i2] + bv);
        }
      }
    }
  }
}

// ---------------------------------------------------------------- flash attention (pipelined)
// S^T = K·Q^T, O^T = V^T·P^T.  64 q rows/block, K-tile 64.
// K double-buffered; V SINGLE-buffered: V(t+1) DMA is issued after the bottom
// barrier of tile t and its latency hides under tile t+1's S-MFMA+softmax phase.
// Per-wave waitcnt chain: [K(t+1) 2ops][V(t+1) 2ops][K(t+2) 2ops] -> vmcnt(2)
// at top of t+1 drains K(t+1)+V(t+1), keeps K(t+2) in flight.
// LDS: Ks[2][64x64] 16KB + Vts[64x64] 8KB + Ps[4][16x64] 8KB = 32KB
//   -> 5 blocks/CU (was 40KB/4): grid 2304 = 9 blocks/CU now runs in rounds
//   5+4 (2T) instead of 4+4+1 (3T). That tail round was the measured 34.6%
//   occupancy ceiling.
// Q consumed directly from global; T13 defer-max; T5 setprio around MFMA.
__global__ __launch_bounds__(256, 5) void attn_fused(const _Float16* __restrict__ Qg,
                                                     const _Float16* __restrict__ Kg,
                                                     const _Float16* __restrict__ Vtg,
                                                     _Float16* __restrict__ Og) {
  __shared__ __align__(16) _Float16 Ks[2][64 * 64];
  __shared__ __align__(16) _Float16 Vts[64 * 64];
  __shared__ __align__(16) _Float16 Ps[4][16 * 64];
  const int tid = threadIdx.x;
  const int wave = tid >> 6, lane = tid & 63;
  const int lo = lane & 15, hi = lane >> 4;
  // XCD-major block mapping: bid%8 = XCD, 18 heads per XCD, 16 q-blocks per head
  const int bid = blockIdx.x;
  const int xcd = bid & 7, idx = bid >> 3;      // idx 0..287
  const int bh = xcd * 18 + (idx >> 4);         // 0..143
  const int q0 = (idx & 15) << 6;
  const _Float16* Qp  = Qg + (bh << 16);
  const _Float16* Kp  = Kg + (bh << 16);
  const _Float16* Vtp = Vtg + (bh << 16);

  // K tile t0 -> Ks[nb] (2 gld16/wave); V tile t0 -> Vts (2 gld16/wave)
  auto issueK = [&](int t0, int nb) {
    #pragma unroll
    for (int j = 0; j < 2; ++j) {
      const int seg = wave * 2 + j;
      gld16(Kp + (t0 + seg * 8 + (lane >> 3)) * 64 + ((lane & 7) << 3), &Ks[nb][seg * 512]);
    }
  };
  auto issueV = [&](int t0) {
    #pragma unroll
    for (int j = 0; j < 2; ++j) {
      const int seg = wave * 2 + j;
      gld16(Vtp + (seg * 8 + (lane >> 3)) * 1024 + t0 + ((lane & 7) << 3), Vts + seg * 512);
    }
  };

  issueK(0, 0);   // prologue: tile 0 K+V in flight
  issueV(0);

  // Q fragment straight from global: lane needs Q[q0+wave*16+lo][ (ks*4+hi)*8 .. +7 ]
  f16x8 qf[2];
  const _Float16* qrow = Qp + (q0 + wave * 16 + lo) * 64;
  qf[0] = *(const f16x8*)(qrow + hi * 8);
  qf[1] = *(const f16x8*)(qrow + (4 + hi) * 8);

  float m_run = -1e30f, l_run = 0.f;
  f32x4 accO[4] = {};
  const float cs = 0.125f * 1.44269504f;  // HD^-0.5 * log2(e)
  _Float16* Pw = Ps[wave];                // wave-private 16q x 64t, xor-swizzled

  auto compute = [&](int cb) {
    const _Float16* Kc = Ks[cb];
    // S^T: C layout col=lo=q, row=hi*4+i (+16*tt) = t
    f32x4 sacc[4] = {};
    __builtin_amdgcn_s_setprio(1);
    #pragma unroll
    for (int tt = 0; tt < 4; ++tt)
      #pragma unroll
      for (int ks = 0; ks < 2; ++ks) {
        const f16x8 kf = *(const f16x8*)(Kc + (tt * 16 + lo) * 64 + (((ks * 4 + hi) ^ (lo & 7)) << 3));
        sacc[tt] = MFMA16(kf, qf[ks], sacc[tt]);
      }
    __builtin_amdgcn_s_setprio(0);
    float rmax = -1e30f;
    #pragma unroll
    for (int tt = 0; tt < 4; ++tt)
      rmax = fmaxf(rmax, fmaxf(fmaxf(sacc[tt][0], sacc[tt][1]), fmaxf(sacc[tt][2], sacc[tt][3])));
    rmax = fmaxf(rmax, __shfl_xor(rmax, 16, 64));
    rmax = fmaxf(rmax, __shfl_xor(rmax, 32, 64));
    // T13 defer-max: if no row's max grew by >8 (wave-uniform check), keep m_run;
    // P is then bounded by 2^8 (fine in f16) and the alpha-rescale is skipped.
    const float rs = rmax * cs;
    const bool nsk = !__all(rs <= m_run + 8.f);
    const float mnew = nsk ? fmaxf(m_run, rs) : m_run;
    const float alpha = nsk ? __builtin_amdgcn_exp2f(m_run - mnew) : 1.f;
    float rsum = 0.f;
    #pragma unroll
    for (int tt = 0; tt < 4; ++tt) {
      const float p0 = __builtin_amdgcn_exp2f(fmaf(sacc[tt][0], cs, -mnew));
      const float p1 = __builtin_amdgcn_exp2f(fmaf(sacc[tt][1], cs, -mnew));
      const float p2 = __builtin_amdgcn_exp2f(fmaf(sacc[tt][2], cs, -mnew));
      const float p3 = __builtin_amdgcn_exp2f(fmaf(sacc[tt][3], cs, -mnew));
      rsum += (p0 + p1) + (p2 + p3);
      union { f16x4 v; h16x2 h[2]; } u;
      u.h[0] = __builtin_amdgcn_cvt_pkrtz(p0, p1);
      u.h[1] = __builtin_amdgcn_cvt_pkrtz(p2, p3);
      const int c = 2 * tt + (hi >> 1);
      *(f16x4*)(Pw + lo * 64 + (((c ^ lo) & 7) << 3) + ((hi & 1) << 2)) = u.v;
    }
    rsum += __shfl_xor(rsum, 16, 64);
    rsum += __shfl_xor(rsum, 32, 64);
    l_run = l_run * alpha + rsum;
    m_run = mnew;
    if (nsk) {
      #pragma unroll
      for (int dt = 0; dt < 4; ++dt) accO[dt] *= alpha;
    }

    // O^T += V^T · P^T (Pw wave-private: no barrier before reads)
    __builtin_amdgcn_s_setprio(1);
    #pragma unroll
    for (int ks2 = 0; ks2 < 2; ++ks2) {
      const int c = 4 * ks2 + hi;
      const f16x8 pf = *(const f16x8*)(Pw + lo * 64 + (((c ^ lo) & 7) << 3));
      #pragma unroll
      for (int dt = 0; dt < 4; ++dt) {
        const int dd = dt * 16 + lo;
        const f16x8 vf = *(const f16x8*)(Vts + dd * 64 + (((c ^ dd) & 7) << 3));
        accO[dt] = MFMA16(vf, pf, accO[dt]);
      }
    }
    __builtin_amdgcn_s_setprio(0);
  };

  // pipelined step: prefetch K(t+1), counted wait for K(t)+V(t), barrier,
  // compute tile t, barrier, then issue V(t+1) (hides under next S+softmax).
  auto step = [&](int tn0, int cb, bool preK, bool preV) {
    if (preK) {
      issueK(tn0, cb ^ 1);
      asm volatile("s_waitcnt vmcnt(2)" ::: "memory");   // K(t),V(t) landed; K(t+1) in flight
    } else {
      asm volatile("s_waitcnt vmcnt(0)" ::: "memory");   // last tile: full drain
    }
    __builtin_amdgcn_sched_barrier(0);
    __builtin_amdgcn_s_barrier();       // cross-wave: tile-t K and V visible
    compute(cb);
    __builtin_amdgcn_sched_barrier(0);
    __builtin_amdgcn_s_barrier();       // all reads of Ks[cb]/Vts done before re-DMA
    if (preV) issueV(tn0);
  };

  #pragma unroll 1
  for (int it = 0; it < 7; ++it) {      // tiles 0..13
    step((2 * it + 1) << 6, 0, true, true);
    step((2 * it + 2) << 6, 1, true, true);
  }
  step(15 << 6, 0, true, true);         // tile 14: prefetch K15, then V15
  step(0, 1, false, false);             // tile 15: drain, no prefetch

  // O^T C layout: col=lo=q, row=hi*4+i (+16*dt) = d. Write Oh [16384,576] swizzled.
  const float inv = 1.f / l_run;
  const int b = bh / 9, hh = bh - b * 9;
  const int rq = (b << 10) + q0 + wave * 16 + lo;
  #pragma unroll
  for (int dt = 0; dt < 4; ++dt) {
    union { f16x4 v; h16x2 h[2]; } u;
    u.h[0] = __builtin_amdgcn_cvt_pkrtz(accO[dt][0] * inv, accO[dt][1] * inv);
    u.h[1] = __builtin_amdgcn_cvt_pkrtz(accO[dt][2] * inv, accO[dt][3] * inv);
    const int c = hh * 8 + dt * 2 + (hi >> 1);
    const int pos = (c & ~7) | ((c ^ rq) & 7);
    *(f16x4*)(Og + rq * 576 + pos * 8 + ((hi & 1) << 2)) = u.v;
  }
}

// ---------------------------------------------------------------- GEMM3: out = O @ proj_w^T + b (fp32 out)
// 1-D grid 768 = 8 XCD x 16 m-tiles x 6 n-tiles, n-inner: A-panel L2-hot per XCD.
__global__ __launch_bounds__(256, 4) void gemm3_proj(const _Float16* __restrict__ A,
                                                     const _Float16* __restrict__ Bw,
                                                     const float* __restrict__ bias,
                                                     float* __restrict__ out) {
  __shared__ __align__(16) _Float16 As[128 * 64];
  __shared__ __align__(16) _Float16 Bs[128 * 64];
  const int tid = threadIdx.x;
  const int wave = tid >> 6, lane = tid & 63;
  const int lo = lane & 15, hi = lane >> 4;
  const int wm = (wave >> 1) * 64, wn = (wave & 1) * 64;
  const int g = blockIdx.x;
  const int xcd = g & 7, i = g >> 3;            // i in [0,96)
  const int mt = i / 6, ntl = i - mt * 6;       // 16 m-tiles/XCD, 6 n-tiles
  const int m0 = (xcd * 16 + mt) * 128, n0 = ntl * 128;
  f32x4 acc[4][4] = {};
  for (int k0 = 0; k0 < 576; k0 += 64) {
    __syncthreads();
    #pragma unroll
    for (int j = 0; j < 4; ++j) {
      const int seg = wave * 4 + j;
      const int gr = seg * 8 + (lane >> 3), gc = (lane & 7) << 3;
      gld16(A + (m0 + gr) * 576 + k0 + gc, As + seg * 512);
      gld16(Bw + (n0 + gr) * 576 + k0 + gc, Bs + seg * 512);
    }
    __syncthreads();
    #pragma unroll
    for (int ks = 0; ks < 2; ++ks) {
      f16x8 af[4], bf[4];
      const int p = ((ks * 4 + hi) ^ (lo & 7)) << 3;
      #pragma unroll
      for (int t = 0; t < 4; ++t) {
        af[t] = *(const f16x8*)(As + (wm + t * 16 + lo) * 64 + p);
        bf[t] = *(const f16x8*)(Bs + (wn + t * 16 + lo) * 64 + p);
      }
      #pragma unroll
      for (int mt2 = 0; mt2 < 4; ++mt2)
        #pragma unroll
        for (int nt = 0; nt < 4; ++nt)
          acc[mt2][nt] = MFMA16(af[mt2], bf[nt], acc[mt2][nt]);
    }
  }
  #pragma unroll
  for (int nt = 0; nt < 4; ++nt) {
    const int n = n0 + wn + nt * 16 + lo;
    const float bv = bias[n];
    #pragma unroll
    for (int mt2 = 0; mt2 < 4; ++mt2) {
      const int mrow = m0 + wm + mt2 * 16 + hi * 4;
      #pragma unroll
      for (int i2 = 0; i2 < 4; ++i2)
        out[(mrow + i2) * 768 + n] = acc[mt2][nt][i2] + bv;
    }
  }
}

// ---------------------------------------------------------------- launch
extern "C" void kernel_launch(void* const* d_in, const int* in_sizes, int n_in,
                              void* d_out, int out_size, void* d_ws, size_t ws_size,
                              hipStream_t stream) {
  const float* x      = (const float*)d_in[0];
  const float* qkv_w  = (const float*)d_in[1];
  const float* qkv_b  = (const float*)d_in[2];
  const float* proj_w = (const float*)d_in[3];
  const float* proj_b = (const float*)d_in[4];
  float* out = (float*)d_out;

  char* ws = (char*)d_ws;
  _Float16* x16 = (_Float16*)(ws + 0);          // 16384*768*2  swz
  _Float16* w1p = (_Float16*)(ws + 25165824);   // 1792*768*2   swz, rows>=1728 zero
  _Float16* w2h = (_Float16*)(ws + 27918336);   // 768*576*2    swz
  _Float16* Qh  = (_Float16*)(ws + 28803072);   // [bh][1024][64] plain
  _Float16* Kh  = (_Float16*)(ws + 47677440);   // [bh][1024][64] swz
  _Float16* Vth = (_Float16*)(ws + 66551808);   // [bh][64][1024] transposed swz
  _Float16* Oh  = (_Float16*)(ws + 85426176);   // [16384][576] swz

  cvt_swz<<<6144, 256, 0, stream>>>(x, x16, 16384, 96, 16384 * 96);
  cvt_swz<<<672, 256, 0, stream>>>(qkv_w, w1p, 1728, 96, 1792 * 96);
  cvt_swz<<<216, 256, 0, stream>>>(proj_w, w2h, 768, 72, 768 * 72);
  gemm1_qkv<<<1792, 256, 0, stream>>>(x16, w1p, qkv_b, Qh, Kh, Vth);
  attn_fused<<<2304, 256, 0, stream>>>(Qh, Kh, Vth, Oh);
  gemm3_proj<<<768, 256, 0, stream>>>(Oh, w2h, proj_b, out);
}